// Round 3
// baseline (209.217 us; speedup 1.0000x reference)
//
#include <hip/hip_runtime.h>
#include <hip/hip_bf16.h>

// Problem constants (B=2, T=4096, D=1024, H=512)
#define TT 4096
#define TD 1024
#define TM 8192            // B*T tokens
#define CN 3072            // big-GEMM N: [U 512 | Vn 512 | P 1024 | Y1 1024]
#define EPS 1e-5f

typedef __bf16 bf16;
typedef __bf16 bf16x4 __attribute__((ext_vector_type(4)));
typedef __bf16 bf16x8 __attribute__((ext_vector_type(8)));
typedef float  f32x4  __attribute__((ext_vector_type(4)));

#define GLOBAL_AS __attribute__((address_space(1)))
#define LDS_AS    __attribute__((address_space(3)))

// ---------------------------------------------------------------------------
// prep: one launch does all input marshalling (unchanged).
// ---------------------------------------------------------------------------
__global__ __launch_bounds__(256) void prep_kernel(const float* __restrict__ x,
                                                   const float* __restrict__ w1,
                                                   const float* __restrict__ wv_w,
                                                   const float* __restrict__ wv_b,
                                                   const float* __restrict__ merge_w,
                                                   bf16* __restrict__ Xbf,
                                                   bf16* __restrict__ BigBT,
                                                   bf16* __restrict__ Amb,
                                                   bf16* __restrict__ WvBf,
                                                   float* __restrict__ cvecP) {
    __shared__ float tile[32][33];
    int b = blockIdx.x;
    const int tid = threadIdx.x;

    if (b < 16) {  // cvec partials: jb = b&3 (256 j's), ec = b>>2 (256 e's)
        const int j = (b & 3) * 256 + tid;
        const int e0 = (b >> 2) * 256;
        const float* col = merge_w + (size_t)(1024 + e0) * 1024 + j;
        float acc = 0.f;
#pragma unroll 32
        for (int e = 0; e < 256; ++e) acc += wv_b[e0 + e] * col[(size_t)e * 1024];
        cvecP[(b >> 2) * 1024 + j] = acc;
        return;
    }
    b -= 16;
    if (b < 8192) {  // cast x
        int i = b * 256 + tid;
        float4 v = ((const float4*)x)[i];
        bf16x4 o; o[0] = (bf16)v.x; o[1] = (bf16)v.y; o[2] = (bf16)v.z; o[3] = (bf16)v.w;
        *(bf16x4*)(Xbf + (size_t)i * 4) = o;
        return;
    }
    b -= 8192;

    const float* src; bf16* dst; int srcN, tilesX, dstOff;
    if (b < 512)       {            src = w1;                        srcN = 512;  tilesX = 16; dst = BigBT; dstOff = 0;    }
    else if (b < 1024) { b -= 512;  src = w1 + (size_t)1024 * 512;   srcN = 512;  tilesX = 16; dst = BigBT; dstOff = 512;  }
    else if (b < 2048) { b -= 1024; src = merge_w;                   srcN = 1024; tilesX = 32; dst = BigBT; dstOff = 2048; }
    else if (b < 3072) { b -= 2048; src = merge_w + (size_t)1024 * 1024; srcN = 1024; tilesX = 32; dst = Amb; dstOff = 0; }
    else {  // cast wv_w
        b -= 3072;
        int i = b * 256 + tid;
        float4 v = ((const float4*)wv_w)[i];
        bf16x4 o; o[0] = (bf16)v.x; o[1] = (bf16)v.y; o[2] = (bf16)v.z; o[3] = (bf16)v.w;
        *(bf16x4*)(WvBf + (size_t)i * 4) = o;
        return;
    }
    int n0 = (b % tilesX) * 32, k0 = (b / tilesX) * 32;
    int tx = tid & 31, ty = tid >> 5;
#pragma unroll
    for (int r = 0; r < 32; r += 8)
        tile[ty + r][tx] = src[(size_t)(k0 + ty + r) * srcN + n0 + tx];
    __syncthreads();
#pragma unroll
    for (int r = 0; r < 32; r += 8)
        dst[(size_t)(dstOff + n0 + ty + r) * 1024 + k0 + tx] = (bf16)tile[tx][ty + r];
}

// ---------------------------------------------------------------------------
// wprime: W' GEMM on 64x64 tiles (grid 257) + cvec reduction (unchanged)
// ---------------------------------------------------------------------------
__global__ __launch_bounds__(256) void wprime_kernel(const bf16* __restrict__ Amb,
                                                     const bf16* __restrict__ WvBf,
                                                     bf16* __restrict__ Wout,
                                                     const float* __restrict__ cvecP,
                                                     float* __restrict__ cvec) {
    int b = blockIdx.x;
    if (b == 256) {
        int j = threadIdx.x * 4;
        float4 s0 = *(const float4*)(cvecP + j);
        float4 s1 = *(const float4*)(cvecP + 1024 + j);
        float4 s2 = *(const float4*)(cvecP + 2048 + j);
        float4 s3 = *(const float4*)(cvecP + 3072 + j);
        float4 o = {s0.x + s1.x + s2.x + s3.x, s0.y + s1.y + s2.y + s3.y,
                    s0.z + s1.z + s2.z + s3.z, s0.w + s1.w + s2.w + s3.w};
        *(float4*)(cvec + j) = o;
        return;
    }
    __shared__ bf16 As[64 * 64];
    __shared__ bf16 Bs[64 * 64];
    const int m0 = (b >> 4) * 64;
    const int n0 = (b & 15) * 64;
    const int tid = threadIdx.x;
    const int wave = tid >> 6, lane = tid & 63;
    const int wr = (wave >> 1) * 32, wc = (wave & 1) * 32;
    const int lrow = lane & 15, cbase = lane >> 4;
    const int sw = lrow & 7;

    f32x4 acc[2][2] = {};

    for (int k0 = 0; k0 < 1024; k0 += 64) {
        __syncthreads();
#pragma unroll
        for (int c = 0; c < 2; ++c) {
            int e = (c * 256 + tid) * 8;
            int row = e >> 6;
            int q = (e >> 3) & 7;
            int gcol = ((q ^ (row & 7)) << 3);
            const bf16* ga = Amb  + (size_t)(m0 + row) * 1024 + k0 + gcol;
            const bf16* gb = WvBf + (size_t)(n0 + row) * 1024 + k0 + gcol;
            __builtin_amdgcn_global_load_lds((const GLOBAL_AS void*)ga,
                                             (LDS_AS void*)(As + e), 16, 0, 0);
            __builtin_amdgcn_global_load_lds((const GLOBAL_AS void*)gb,
                                             (LDS_AS void*)(Bs + e), 16, 0, 0);
        }
        __syncthreads();

#pragma unroll
        for (int kk = 0; kk < 2; ++kk) {
            const int qo = ((cbase + kk * 4) ^ sw) << 3;
            bf16x8 af[2], bfr[2];
#pragma unroll
            for (int i = 0; i < 2; ++i) {
                af[i]  = *(const bf16x8*)(As + (wr + i * 16 + lrow) * 64 + qo);
                bfr[i] = *(const bf16x8*)(Bs + (wc + i * 16 + lrow) * 64 + qo);
            }
#pragma unroll
            for (int i = 0; i < 2; ++i)
#pragma unroll
                for (int j = 0; j < 2; ++j)
                    acc[i][j] = __builtin_amdgcn_mfma_f32_16x16x32_bf16(af[i], bfr[j], acc[i][j], 0, 0, 0);
        }
    }

    const int lr = (lane >> 4) * 4, lc = lane & 15;
#pragma unroll
    for (int i = 0; i < 2; ++i)
#pragma unroll
        for (int j = 0; j < 2; ++j)
#pragma unroll
            for (int r = 0; r < 4; ++r)
                Wout[(size_t)(m0 + wr + i * 16 + lr + r) * 1024 + (n0 + wc + j * 16 + lc)]
                    = (bf16)acc[i][j][r];
}

// ---------------------------------------------------------------------------
// Big GEMM v3: identical structure to v2 (BM=256 x BN=384, BK=64, 8 waves of
// 128x96, acc[8][6], LDS 160 KiB, 256 blocks = 1 pass, conflict-free XOR
// swizzle verified by r2's counter drop 2.49M -> 393K).
//
// ONE change vs r2: __launch_bounds__(512, 1) instead of (512, 2).
// r2's (512,2) capped VGPRs at 128 (4 waves/SIMD budget) while the kernel
// needs ~245 (acc alone = 192) -> accumulator spilled to scratch every
// phase: VGPR_Count=128, FETCH +19MB, WRITE +21MB, MfmaUtil 28%, 71 us.
// LDS=160KiB already limits residency to 1 block/CU, so (512,2) bought
// nothing. (512,1) = HK-verified regime: 512 thr, 256 VGPR, 1 block/CU.
// ---------------------------------------------------------------------------
#define MFMA16(a, b, c) __builtin_amdgcn_mfma_f32_16x16x32_bf16((a), (b), (c), 0, 0, 0)

// LDS layout (bf16 elems): buf* = BUF*40960; A at +0 (256x64), B at +16384 (384x64)
#define STAGE_A(BUF, T) do {                                                      \
    _Pragma("unroll")                                                             \
    for (int ld_ = 0; ld_ < 4; ++ld_) {                                           \
        const bf16* ga_ = aBase + (size_t)(ld_ * 64) * 1024 + (T) * 64;           \
        __builtin_amdgcn_global_load_lds((const GLOBAL_AS void*)ga_,              \
            (LDS_AS void*)(SMEM + (BUF) * 40960 + ld_ * 4096 + tid * 8), 16, 0, 0); \
    } } while (0)

#define STAGE_B(BUF, T, L0, L1) do {                                              \
    _Pragma("unroll")                                                             \
    for (int ld_ = (L0); ld_ < (L1); ++ld_) {                                     \
        const bf16* gb_ = bBase + (size_t)(ld_ * 64) * 1024 + (T) * 64;           \
        __builtin_amdgcn_global_load_lds((const GLOBAL_AS void*)gb_,              \
            (LDS_AS void*)(SMEM + (BUF) * 40960 + 16384 + ld_ * 4096 + tid * 8), 16, 0, 0); \
    } } while (0)

#define AF(BUF, I, KK) (*(const bf16x8*)(SMEM + (BUF) * 40960 +                   \
    (wm * 128 + (I) * 16 + lrow) * 64 + (((cbase + (KK) * 4) ^ sw) << 3)))
#define BF(BUF, J, KK) (*(const bf16x8*)(SMEM + (BUF) * 40960 + 16384 +           \
    (wn * 96 + (J) * 16 + lrow) * 64 + (((cbase + (KK) * 4) ^ sw) << 3)))

#define NOSTAGE do {} while (0)
#define NOGATE  do {} while (0)
#define GATE0 do { asm volatile("s_waitcnt vmcnt(0)" ::: "memory");               \
                   __builtin_amdgcn_sched_barrier(0); } while (0)

// Phase: (KK, H): af i = H*4..H*4+3, 24 MFMA. RDB: refresh bfr[] for this KK.
#define PH(BUF, KK, H, RDB, STAGE, GATE) do {                                     \
    if (RDB) {                                                                    \
        _Pragma("unroll")                                                         \
        for (int j = 0; j < 6; ++j) bfr[j] = BF(BUF, j, KK);                      \
    }                                                                             \
    bf16x8 a0_ = AF(BUF, (H) * 4 + 0, KK);                                        \
    bf16x8 a1_ = AF(BUF, (H) * 4 + 1, KK);                                        \
    bf16x8 a2_ = AF(BUF, (H) * 4 + 2, KK);                                        \
    bf16x8 a3_ = AF(BUF, (H) * 4 + 3, KK);                                        \
    STAGE;                                                                        \
    __builtin_amdgcn_s_barrier();                                                 \
    __builtin_amdgcn_sched_barrier(0);                                            \
    __builtin_amdgcn_s_setprio(1);                                                \
    _Pragma("unroll")                                                             \
    for (int j = 0; j < 6; ++j) {                                                 \
        acc[(H) * 4 + 0][j] = MFMA16(a0_, bfr[j], acc[(H) * 4 + 0][j]);           \
        acc[(H) * 4 + 1][j] = MFMA16(a1_, bfr[j], acc[(H) * 4 + 1][j]);           \
        acc[(H) * 4 + 2][j] = MFMA16(a2_, bfr[j], acc[(H) * 4 + 2][j]);           \
        acc[(H) * 4 + 3][j] = MFMA16(a3_, bfr[j], acc[(H) * 4 + 3][j]);           \
    }                                                                             \
    __builtin_amdgcn_s_setprio(0);                                                \
    GATE;                                                                         \
    __builtin_amdgcn_s_barrier();                                                 \
    __builtin_amdgcn_sched_barrier(0);                                            \
} while (0)

// One K-tile (4 phases). S0/S1/S2 staging for tile t+1; G3 gate at end.
#define TILE(BUF, S0, S1, S2, G3)                                                 \
    PH(BUF, 0, 0, 1, S0, NOGATE);                                                 \
    PH(BUF, 0, 1, 0, S1, NOGATE);                                                 \
    PH(BUF, 1, 0, 1, S2, NOGATE);                                                 \
    PH(BUF, 1, 1, 0, NOSTAGE, G3);

__global__ __launch_bounds__(512, 1) void gemm_big(const bf16* __restrict__ A,
                                                   const bf16* __restrict__ BT,
                                                   bf16* __restrict__ C) {
    __shared__ __align__(16) bf16 SMEM[81920];   // 163840 B = 160 KiB exactly
    const int NB = 3072, K = 1024;

    const int L = blockIdx.x;            // 0..255
    const int m0 = (L >> 3) * 256;       // 32 M-tiles
    const int n0 = (L & 7) * 384;        // 8 N-tiles; XCD x gets n-stripe x
    const int tid = threadIdx.x;
    const int wave = tid >> 6, lane = tid & 63;
    const int wm = wave >> 2;            // 0..1 -> M offset wm*128
    const int wn = wave & 3;             // 0..3 -> N offset wn*96
    const int lrow = lane & 15, cbase = lane >> 4;
    const int sw = lrow & 7;

    // staging source bases (per-thread; ld/t offsets added in macros)
    const int r0 = tid >> 3;                               // 0..63
    const int c0 = ((tid & 7) ^ ((tid >> 3) & 7)) << 3;    // pre-swizzled col
    const bf16* aBase = A  + (size_t)(m0 + r0) * K + c0;
    const bf16* bBase = BT + (size_t)(n0 + r0) * K + c0;

    f32x4 acc[8][6] = {};
    bf16x8 bfr[6];

    // ---- prologue: stage tile 0 fully, drain, barrier ----
    STAGE_A(0, 0);
    STAGE_B(0, 0, 0, 6);
    asm volatile("s_waitcnt vmcnt(0)" ::: "memory");
    __builtin_amdgcn_sched_barrier(0);
    __builtin_amdgcn_s_barrier();
    __builtin_amdgcn_sched_barrier(0);

    // ---- main loop: tiles 0..13 (7 iters x 2 tiles), staging 1 tile ahead
    for (int i = 0; i < 7; ++i) {
        const int t1 = 2 * i + 1, t2 = 2 * i + 2;
        TILE(0, STAGE_A(1, t1), STAGE_B(1, t1, 0, 3), STAGE_B(1, t1, 3, 6), GATE0);
        TILE(1, STAGE_A(0, t2), STAGE_B(0, t2, 0, 3), STAGE_B(0, t2, 3, 6), GATE0);
    }
    // tile 14 (stage 15), tile 15 (no stage)
    TILE(0, STAGE_A(1, 15), STAGE_B(1, 15, 0, 3), STAGE_B(1, 15, 3, 6), GATE0);
    TILE(1, NOSTAGE, NOSTAGE, NOSTAGE, NOGATE);

    // ---- Epilogue: 2 rounds of 64 rows via wave-local LDS repack ----
    __syncthreads();                       // all waves done with staging LDS
    bf16* ep = SMEM + wave * 6656;         // 64 rows x 104 stride per wave
    const int lr = (lane >> 4) * 4, lc = lane & 15;
#pragma unroll
    for (int h = 0; h < 2; ++h) {
#pragma unroll
        for (int ii = 0; ii < 4; ++ii)
#pragma unroll
            for (int j = 0; j < 6; ++j)
#pragma unroll
                for (int r = 0; r < 4; ++r)
                    ep[(ii * 16 + lr + r) * 104 + (j * 16 + lc)]
                        = (bf16)acc[h * 4 + ii][j][r];
        __syncthreads();
        bf16* Cw = C + (size_t)(m0 + wm * 128 + h * 64) * NB + n0 + wn * 96;
        // cols 0..63: 8 insts, 8 rows x 8 lanes x 16B
#pragma unroll
        for (int p = 0; p < 8; ++p) {
            int R = p * 8 + (lane >> 3);
            int Ccol = (lane & 7) * 8;
            bf16x8 v = *(const bf16x8*)(ep + R * 104 + Ccol);
            *(bf16x8*)(Cw + (size_t)R * NB + Ccol) = v;
        }
        // cols 64..95: 4 insts, 16 rows x 4 lanes x 16B
#pragma unroll
        for (int p = 0; p < 4; ++p) {
            int R = p * 16 + (lane >> 2);
            int Ccol = 64 + (lane & 3) * 8;
            bf16x8 v = *(const bf16x8*)(ep + R * 104 + Ccol);
            *(bf16x8*)(Cw + (size_t)R * NB + Ccol) = v;
        }
        __syncthreads();
    }
}

// ---------------------------------------------------------------------------
// final: wave-per-token, 4 tokens/block, zero __syncthreads (unchanged).
// ---------------------------------------------------------------------------
__global__ __launch_bounds__(256) void final_kernel(const bf16* __restrict__ C,
                                                    const float* __restrict__ b1,
                                                    const float* __restrict__ b2,
                                                    const float* __restrict__ w2,
                                                    const float* __restrict__ cvec,
                                                    const float* __restrict__ merge_b,
                                                    const float* __restrict__ gamma,
                                                    const float* __restrict__ beta,
                                                    float* __restrict__ out) {
    const int wave = threadIdx.x >> 6, lane = threadIdx.x & 63;
    const int row = blockIdx.x * 4 + wave;
    const int t = row & (TT - 1);
    const bf16* Crow = C + (size_t)row * CN;

    const int h0 = lane * 8;
    bf16x8 u8 = *(const bf16x8*)(Crow + h0);
    float4 b1a = *(const float4*)(b1 + h0), b1b = *(const float4*)(b1 + h0 + 4);
    float4 w2a = *(const float4*)(w2 + h0), w2b = *(const float4*)(w2 + h0 + 4);
    float u[8] = {(float)u8[0] + b1a.x, (float)u8[1] + b1a.y,
                  (float)u8[2] + b1a.z, (float)u8[3] + b1a.w,
                  (float)u8[4] + b1b.x, (float)u8[5] + b1b.y,
                  (float)u8[6] + b1b.z, (float)u8[7] + b1b.w};
    const float w2v[8] = {w2a.x, w2a.y, w2a.z, w2a.w, w2b.x, w2b.y, w2b.z, w2b.w};

    float partial[4];
#pragma unroll
    for (int w = 0; w < 4; ++w) {
        float p = 0.f;
        if (t >= w + 1) {
            bf16x8 v8 = *(const bf16x8*)(C + (size_t)(row - w - 1) * CN + 512 + h0);
#pragma unroll
            for (int k = 0; k < 8; ++k) {
                float z = u[k] + (float)v8[k];
                p += (z / (1.f + __expf(-z))) * w2v[k];
            }
        } else {
#pragma unroll
            for (int k = 0; k < 8; ++k) {
                float z = u[k];
                p += (z / (1.f + __expf(-z))) * w2v[k];
            }
        }
        partial[w] = p;
    }
#pragma unroll
    for (int w = 0; w < 4; ++w)
#pragma unroll
        for (int off = 1; off < 64; off <<= 1)
            partial[w] += __shfl_xor(partial[w], off, 64);

    const float bias2 = b2[0];
    float taus[4];
#pragma unroll
    for (int w = 0; w < 4; ++w)
        taus[w] = 1.f / (1.f + __expf(-(partial[w] + bias2)));
    const float tsum = taus[0] + taus[1] + taus[2] + taus[3];

    const int d0 = lane * 16;
    bf16x8 y1a = *(const bf16x8*)(Crow + 2048 + d0);
    bf16x8 y1b = *(const bf16x8*)(Crow + 2048 + d0 + 8);
    float v[16];
#pragma unroll
    for (int k = 0; k < 8; ++k) { v[k] = (float)y1a[k]; v[8 + k] = (float)y1b[k]; }
#pragma unroll
    for (int q = 0; q < 4; ++q) {
        float4 cv = *(const float4*)(cvec + d0 + q * 4);
        float4 mb = *(const float4*)(merge_b + d0 + q * 4);
        v[q*4+0] += tsum * cv.x + mb.x; v[q*4+1] += tsum * cv.y + mb.y;
        v[q*4+2] += tsum * cv.z + mb.z; v[q*4+3] += tsum * cv.w + mb.w;
    }
#pragma unroll
    for (int w = 0; w < 4; ++w) {
        if (t >= w + 1) {
            const bf16* Pn = C + (size_t)(row - w - 1) * CN + 1024 + d0;
            bf16x8 pa = *(const bf16x8*)Pn;
            bf16x8 pb = *(const bf16x8*)(Pn + 8);
#pragma unroll
            for (int k = 0; k < 8; ++k) {
                v[k] += taus[w] * (float)pa[k];
                v[8 + k] += taus[w] * (float)pb[k];
            }
        }
    }

    float s = 0.f, ss = 0.f;
#pragma unroll
    for (int k = 0; k < 16; ++k) { s += v[k]; ss += v[k] * v[k]; }
#pragma unroll
    for (int off = 1; off < 64; off <<= 1) {
        s  += __shfl_xor(s, off, 64);
        ss += __shfl_xor(ss, off, 64);
    }
    const float mu = s * (1.f / TD);
    const float var = ss * (1.f / TD) - mu * mu;
    const float r = rsqrtf(var + EPS);

#pragma unroll
    for (int q = 0; q < 4; ++q) {
        float4 g  = *(const float4*)(gamma + d0 + q * 4);
        float4 bt = *(const float4*)(beta + d0 + q * 4);
        float4 o;
        o.x = (v[q*4+0] - mu) * r * g.x + bt.x;
        o.y = (v[q*4+1] - mu) * r * g.y + bt.y;
        o.z = (v[q*4+2] - mu) * r * g.z + bt.z;
        o.w = (v[q*4+3] - mu) * r * g.w + bt.w;
        *(float4*)(out + (size_t)row * TD + d0 + q * 4) = o;
    }
}

// ---------------------------------------------------------------------------
extern "C" void kernel_launch(void* const* d_in, const int* in_sizes, int n_in,
                              void* d_out, int out_size, void* d_ws, size_t ws_size,
                              hipStream_t stream) {
    const float* x       = (const float*)d_in[0];
    const float* w1      = (const float*)d_in[1];
    const float* b1      = (const float*)d_in[2];
    const float* w2      = (const float*)d_in[3];
    const float* b2      = (const float*)d_in[4];
    const float* wv_w    = (const float*)d_in[5];
    const float* wv_b    = (const float*)d_in[6];
    const float* merge_w = (const float*)d_in[7];
    const float* merge_b = (const float*)d_in[8];
    const float* gamma   = (const float*)d_in[9];
    const float* beta    = (const float*)d_in[10];
    float* out = (float*)d_out;

    char* ws = (char*)d_ws;
    bf16*  Xbf   = (bf16*)ws;  ws += (size_t)TM * 1024 * 2;    // [8192][1024]
    bf16*  BigBT = (bf16*)ws;  ws += (size_t)CN * 1024 * 2;    // [3072 n][1024 k]
    bf16*  Amb   = (bf16*)ws;  ws += (size_t)1024 * 1024 * 2;  // merge_bot^T [j][e]
    bf16*  WvBf  = (bf16*)ws;  ws += (size_t)1024 * 1024 * 2;  // wv_w bf16
    float* cvecP = (float*)ws; ws += (size_t)4 * 1024 * 4;     // partials
    float* cvec  = (float*)ws; ws += (size_t)1024 * 4;         // wv_b @ merge_bot
    bf16*  Cbuf  = (bf16*)ws;                                  // [8192][3072]

    // 1. marshal everything (one launch)
    prep_kernel<<<12304, 256, 0, stream>>>(x, w1, wv_w, wv_b, merge_w,
                                           Xbf, BigBT, Amb, WvBf, cvecP);

    // 2. W' GEMM (full-GPU 64x64 tiles) + cvec reduction
    wprime_kernel<<<257, 256, 0, stream>>>(Amb, WvBf, BigBT + (size_t)1024 * 1024,
                                           cvecP, cvec);

    // 3. big GEMM: Cbuf = Xbf @ BigBT^T   (M=8192, N=3072, K=1024)
    //    256x384 tiles, 8 waves of 128x96, 256 blocks = 1 residency pass
    gemm_big<<<256, 512, 0, stream>>>(Xbf, BigBT, Cbuf);

    // 4. fused tau + combine + LayerNorm (wave-per-token, no barriers)
    final_kernel<<<TM / 4, 256, 0, stream>>>(Cbuf, b1, b2, w2, cvec, merge_b,
                                             gamma, beta, out);
}

// Round 4
// 202.932 us; speedup vs baseline: 1.0310x; 1.0310x over previous
//
#include <hip/hip_runtime.h>
#include <hip/hip_bf16.h>

// Problem constants (B=2, T=4096, D=1024, H=512)
#define TT 4096
#define TD 1024
#define TM 8192            // B*T tokens
#define CN 3072            // big-GEMM N: [U 512 | Vn 512 | P 1024 | Y1 1024]
#define EPS 1e-5f

typedef __bf16 bf16;
typedef __bf16 bf16x4 __attribute__((ext_vector_type(4)));
typedef __bf16 bf16x8 __attribute__((ext_vector_type(8)));
typedef float  f32x4  __attribute__((ext_vector_type(4)));

#define GLOBAL_AS __attribute__((address_space(1)))
#define LDS_AS    __attribute__((address_space(3)))

// ---------------------------------------------------------------------------
// prep: one launch does all input marshalling (unchanged).
// ---------------------------------------------------------------------------
__global__ __launch_bounds__(256) void prep_kernel(const float* __restrict__ x,
                                                   const float* __restrict__ w1,
                                                   const float* __restrict__ wv_w,
                                                   const float* __restrict__ wv_b,
                                                   const float* __restrict__ merge_w,
                                                   bf16* __restrict__ Xbf,
                                                   bf16* __restrict__ BigBT,
                                                   bf16* __restrict__ Amb,
                                                   bf16* __restrict__ WvBf,
                                                   float* __restrict__ cvecP) {
    __shared__ float tile[32][33];
    int b = blockIdx.x;
    const int tid = threadIdx.x;

    if (b < 16) {  // cvec partials: jb = b&3 (256 j's), ec = b>>2 (256 e's)
        const int j = (b & 3) * 256 + tid;
        const int e0 = (b >> 2) * 256;
        const float* col = merge_w + (size_t)(1024 + e0) * 1024 + j;
        float acc = 0.f;
#pragma unroll 32
        for (int e = 0; e < 256; ++e) acc += wv_b[e0 + e] * col[(size_t)e * 1024];
        cvecP[(b >> 2) * 1024 + j] = acc;
        return;
    }
    b -= 16;
    if (b < 8192) {  // cast x
        int i = b * 256 + tid;
        float4 v = ((const float4*)x)[i];
        bf16x4 o; o[0] = (bf16)v.x; o[1] = (bf16)v.y; o[2] = (bf16)v.z; o[3] = (bf16)v.w;
        *(bf16x4*)(Xbf + (size_t)i * 4) = o;
        return;
    }
    b -= 8192;

    const float* src; bf16* dst; int srcN, tilesX, dstOff;
    if (b < 512)       {            src = w1;                        srcN = 512;  tilesX = 16; dst = BigBT; dstOff = 0;    }
    else if (b < 1024) { b -= 512;  src = w1 + (size_t)1024 * 512;   srcN = 512;  tilesX = 16; dst = BigBT; dstOff = 512;  }
    else if (b < 2048) { b -= 1024; src = merge_w;                   srcN = 1024; tilesX = 32; dst = BigBT; dstOff = 2048; }
    else if (b < 3072) { b -= 2048; src = merge_w + (size_t)1024 * 1024; srcN = 1024; tilesX = 32; dst = Amb; dstOff = 0; }
    else {  // cast wv_w
        b -= 3072;
        int i = b * 256 + tid;
        float4 v = ((const float4*)wv_w)[i];
        bf16x4 o; o[0] = (bf16)v.x; o[1] = (bf16)v.y; o[2] = (bf16)v.z; o[3] = (bf16)v.w;
        *(bf16x4*)(WvBf + (size_t)i * 4) = o;
        return;
    }
    int n0 = (b % tilesX) * 32, k0 = (b / tilesX) * 32;
    int tx = tid & 31, ty = tid >> 5;
#pragma unroll
    for (int r = 0; r < 32; r += 8)
        tile[ty + r][tx] = src[(size_t)(k0 + ty + r) * srcN + n0 + tx];
    __syncthreads();
#pragma unroll
    for (int r = 0; r < 32; r += 8)
        dst[(size_t)(dstOff + n0 + ty + r) * 1024 + k0 + tx] = (bf16)tile[tx][ty + r];
}

// ---------------------------------------------------------------------------
// wprime: W' GEMM on 64x64 tiles (grid 257) + cvec reduction (unchanged)
// ---------------------------------------------------------------------------
__global__ __launch_bounds__(256) void wprime_kernel(const bf16* __restrict__ Amb,
                                                     const bf16* __restrict__ WvBf,
                                                     bf16* __restrict__ Wout,
                                                     const float* __restrict__ cvecP,
                                                     float* __restrict__ cvec) {
    int b = blockIdx.x;
    if (b == 256) {
        int j = threadIdx.x * 4;
        float4 s0 = *(const float4*)(cvecP + j);
        float4 s1 = *(const float4*)(cvecP + 1024 + j);
        float4 s2 = *(const float4*)(cvecP + 2048 + j);
        float4 s3 = *(const float4*)(cvecP + 3072 + j);
        float4 o = {s0.x + s1.x + s2.x + s3.x, s0.y + s1.y + s2.y + s3.y,
                    s0.z + s1.z + s2.z + s3.z, s0.w + s1.w + s2.w + s3.w};
        *(float4*)(cvec + j) = o;
        return;
    }
    __shared__ bf16 As[64 * 64];
    __shared__ bf16 Bs[64 * 64];
    const int m0 = (b >> 4) * 64;
    const int n0 = (b & 15) * 64;
    const int tid = threadIdx.x;
    const int wave = tid >> 6, lane = tid & 63;
    const int wr = (wave >> 1) * 32, wc = (wave & 1) * 32;
    const int lrow = lane & 15, cbase = lane >> 4;
    const int sw = lrow & 7;

    f32x4 acc[2][2] = {};

    for (int k0 = 0; k0 < 1024; k0 += 64) {
        __syncthreads();
#pragma unroll
        for (int c = 0; c < 2; ++c) {
            int e = (c * 256 + tid) * 8;
            int row = e >> 6;
            int q = (e >> 3) & 7;
            int gcol = ((q ^ (row & 7)) << 3);
            const bf16* ga = Amb  + (size_t)(m0 + row) * 1024 + k0 + gcol;
            const bf16* gb = WvBf + (size_t)(n0 + row) * 1024 + k0 + gcol;
            __builtin_amdgcn_global_load_lds((const GLOBAL_AS void*)ga,
                                             (LDS_AS void*)(As + e), 16, 0, 0);
            __builtin_amdgcn_global_load_lds((const GLOBAL_AS void*)gb,
                                             (LDS_AS void*)(Bs + e), 16, 0, 0);
        }
        __syncthreads();

#pragma unroll
        for (int kk = 0; kk < 2; ++kk) {
            const int qo = ((cbase + kk * 4) ^ sw) << 3;
            bf16x8 af[2], bfr[2];
#pragma unroll
            for (int i = 0; i < 2; ++i) {
                af[i]  = *(const bf16x8*)(As + (wr + i * 16 + lrow) * 64 + qo);
                bfr[i] = *(const bf16x8*)(Bs + (wc + i * 16 + lrow) * 64 + qo);
            }
#pragma unroll
            for (int i = 0; i < 2; ++i)
#pragma unroll
                for (int j = 0; j < 2; ++j)
                    acc[i][j] = __builtin_amdgcn_mfma_f32_16x16x32_bf16(af[i], bfr[j], acc[i][j], 0, 0, 0);
        }
    }

    const int lr = (lane >> 4) * 4, lc = lane & 15;
#pragma unroll
    for (int i = 0; i < 2; ++i)
#pragma unroll
        for (int j = 0; j < 2; ++j)
#pragma unroll
            for (int r = 0; r < 4; ++r)
                Wout[(size_t)(m0 + wr + i * 16 + lr + r) * 1024 + (n0 + wc + j * 16 + lc)]
                    = (bf16)acc[i][j][r];
}

// ---------------------------------------------------------------------------
// Big GEMM v4: 4-wave block (256 thr), BM=256 x BN=192, wave = 128x96
// (acc[8][6] = 192 AGPR).
//
// WHY 4 waves (the r2/r3 lesson): an 8-wave block forces 2 waves/SIMD
// co-residency, capping per-wave regs at 256 (unified VGPR+AGPR).
// acc[8][6]=192 + ~90 arch > 256 -> unavoidable spill (r2/r3: VGPR=128,
// +27 MB scratch WRITE, 71->85 us). A 4-wave block = 1 wave/SIMD -> 512-reg
// budget -> fits with headroom. r0's 184-reg config confirms the cap model.
//
// WHY 128x96 per wave: per CU per K-tile at ~100 B/cyc LDS:
//   r0 (8x 64x96 waves/CU): 164 KB frag-read + 90 KB stage = ~2540 LDS-cyc
//      vs 1866 MFMA-cyc -> LDS-bound (measured 37% util).
//   v4 (4x 128x96):        115 KB + 57 KB = ~1720 LDS-cyc vs 1866 MFMA-cyc
//      -> MFMA becomes the long pole.
// Grid 32x16 = 512 blocks = exactly 2 full 1-block/CU passes. LDS 112 KiB.
// Same verified 4-phase schedule + XOR swizzle as r2/r3 (numerically
// correct there; only wave count / layout constants change).
// XCD swizzle: xcd = L&7 owns n-stripes {2*xcd, 2*xcd+1} (768 KB B, L2-res).
// ---------------------------------------------------------------------------
#define MFMA16(a, b, c) __builtin_amdgcn_mfma_f32_16x16x32_bf16((a), (b), (c), 0, 0, 0)

// LDS (bf16 el): buf = BUF*28672.  A at +0 (256x64=16384), B at +16384 (192x64=12288)
#define STAGE_A(BUF, T, L0, L1) do {                                              \
    _Pragma("unroll")                                                             \
    for (int ld_ = (L0); ld_ < (L1); ++ld_) {                                     \
        const bf16* ga_ = aBase + (size_t)(ld_ * 32) * 1024 + (T) * 64;           \
        __builtin_amdgcn_global_load_lds((const GLOBAL_AS void*)ga_,              \
            (LDS_AS void*)(SMEM + (BUF) * 28672 + ld_ * 2048 + tid * 8), 16, 0, 0); \
    } } while (0)

#define STAGE_B(BUF, T, L0, L1) do {                                              \
    _Pragma("unroll")                                                             \
    for (int ld_ = (L0); ld_ < (L1); ++ld_) {                                     \
        const bf16* gb_ = bBase + (size_t)(ld_ * 32) * 1024 + (T) * 64;           \
        __builtin_amdgcn_global_load_lds((const GLOBAL_AS void*)gb_,              \
            (LDS_AS void*)(SMEM + (BUF) * 28672 + 16384 + ld_ * 2048 + tid * 8), 16, 0, 0); \
    } } while (0)

#define AF(BUF, I, KK) (*(const bf16x8*)(SMEM + (BUF) * 28672 +                   \
    (wm * 128 + (I) * 16 + lrow) * 64 + (((cbase + (KK) * 4) ^ sw) << 3)))
#define BF(BUF, J, KK) (*(const bf16x8*)(SMEM + (BUF) * 28672 + 16384 +           \
    (wn * 96 + (J) * 16 + lrow) * 64 + (((cbase + (KK) * 4) ^ sw) << 3)))

#define NOSTAGE do {} while (0)
#define NOGATE  do {} while (0)
#define GATE0 do { asm volatile("s_waitcnt vmcnt(0)" ::: "memory");               \
                   __builtin_amdgcn_sched_barrier(0); } while (0)

// Phase: (KK, H): af i = H*4..H*4+3, 24 MFMA. RDB: refresh bfr[] for this KK.
#define PH(BUF, KK, H, RDB, STAGE, GATE) do {                                     \
    if (RDB) {                                                                    \
        _Pragma("unroll")                                                         \
        for (int j = 0; j < 6; ++j) bfr[j] = BF(BUF, j, KK);                      \
    }                                                                             \
    bf16x8 a0_ = AF(BUF, (H) * 4 + 0, KK);                                        \
    bf16x8 a1_ = AF(BUF, (H) * 4 + 1, KK);                                        \
    bf16x8 a2_ = AF(BUF, (H) * 4 + 2, KK);                                        \
    bf16x8 a3_ = AF(BUF, (H) * 4 + 3, KK);                                        \
    STAGE;                                                                        \
    __builtin_amdgcn_s_barrier();                                                 \
    __builtin_amdgcn_sched_barrier(0);                                            \
    __builtin_amdgcn_s_setprio(1);                                                \
    _Pragma("unroll")                                                             \
    for (int j = 0; j < 6; ++j) {                                                 \
        acc[(H) * 4 + 0][j] = MFMA16(a0_, bfr[j], acc[(H) * 4 + 0][j]);           \
        acc[(H) * 4 + 1][j] = MFMA16(a1_, bfr[j], acc[(H) * 4 + 1][j]);           \
        acc[(H) * 4 + 2][j] = MFMA16(a2_, bfr[j], acc[(H) * 4 + 2][j]);           \
        acc[(H) * 4 + 3][j] = MFMA16(a3_, bfr[j], acc[(H) * 4 + 3][j]);           \
    }                                                                             \
    __builtin_amdgcn_s_setprio(0);                                                \
    GATE;                                                                         \
    __builtin_amdgcn_s_barrier();                                                 \
    __builtin_amdgcn_sched_barrier(0);                                            \
} while (0)

// One K-tile (4 phases). S0/S1/S2 stage tile t+1 (A 8 loads, B 6); gate at p3.
#define TILE(BUF, S0, S1, S2, G3)                                                 \
    PH(BUF, 0, 0, 1, S0, NOGATE);                                                 \
    PH(BUF, 0, 1, 0, S1, NOGATE);                                                 \
    PH(BUF, 1, 0, 1, S2, NOGATE);                                                 \
    PH(BUF, 1, 1, 0, NOSTAGE, G3);

__global__ __launch_bounds__(256, 1) void gemm_big(const bf16* __restrict__ A,
                                                   const bf16* __restrict__ BT,
                                                   bf16* __restrict__ C) {
    __shared__ __align__(16) bf16 SMEM[57344];   // 114688 B = 112 KiB
    const int NB = 3072, K = 1024;

    const int L = blockIdx.x;            // 0..511
    const int m0 = (L >> 4) * 256;       // 32 M-tiles
    const int n0 = ((L & 7) * 2 + ((L >> 3) & 1)) * 192;  // XCD x -> stripes {2x,2x+1}
    const int tid = threadIdx.x;
    const int wave = tid >> 6, lane = tid & 63;
    const int wm = wave >> 1;            // 0..1 -> M offset wm*128
    const int wn = wave & 1;             // 0..1 -> N offset wn*96
    const int lrow = lane & 15, cbase = lane >> 4;
    const int sw = lrow & 7;

    // staging source bases (per-thread; ld/t offsets added in macros)
    const int r0 = tid >> 3;                               // 0..31
    const int c0 = ((tid & 7) ^ ((tid >> 3) & 7)) << 3;    // pre-swizzled col
    const bf16* aBase = A  + (size_t)(m0 + r0) * K + c0;
    const bf16* bBase = BT + (size_t)(n0 + r0) * K + c0;

    f32x4 acc[8][6] = {};
    bf16x8 bfr[6];

    // ---- prologue: stage tile 0 fully, drain, barrier ----
    STAGE_A(0, 0, 0, 8);
    STAGE_B(0, 0, 0, 6);
    asm volatile("s_waitcnt vmcnt(0)" ::: "memory");
    __builtin_amdgcn_sched_barrier(0);
    __builtin_amdgcn_s_barrier();
    __builtin_amdgcn_sched_barrier(0);

    // ---- main loop: tiles 0..13 (7 iters x 2 tiles), staging 1 tile ahead
    for (int i = 0; i < 7; ++i) {
        const int t1 = 2 * i + 1, t2 = 2 * i + 2;
        TILE(0, STAGE_A(1, t1, 0, 4), STAGE_A(1, t1, 4, 8), STAGE_B(1, t1, 0, 6), GATE0);
        TILE(1, STAGE_A(0, t2, 0, 4), STAGE_A(0, t2, 4, 8), STAGE_B(0, t2, 0, 6), GATE0);
    }
    // tile 14 (stage 15), tile 15 (no stage)
    TILE(0, STAGE_A(1, 15, 0, 4), STAGE_A(1, 15, 4, 8), STAGE_B(1, 15, 0, 6), GATE0);
    TILE(1, NOSTAGE, NOSTAGE, NOSTAGE, NOGATE);

    // ---- Epilogue: 2 rounds of 64 rows via wave-local LDS repack ----
    __syncthreads();                       // all waves done with staging LDS
    bf16* ep = SMEM + wave * 6656;         // 64 rows x 104 stride per wave
    const int lr = (lane >> 4) * 4, lc = lane & 15;
#pragma unroll
    for (int h = 0; h < 2; ++h) {
#pragma unroll
        for (int ii = 0; ii < 4; ++ii)
#pragma unroll
            for (int j = 0; j < 6; ++j)
#pragma unroll
                for (int r = 0; r < 4; ++r)
                    ep[(ii * 16 + lr + r) * 104 + (j * 16 + lc)]
                        = (bf16)acc[h * 4 + ii][j][r];
        __syncthreads();
        bf16* Cw = C + (size_t)(m0 + wm * 128 + h * 64) * NB + n0 + wn * 96;
        // cols 0..63: 8 insts, 8 rows x 8 lanes x 16B
#pragma unroll
        for (int p = 0; p < 8; ++p) {
            int R = p * 8 + (lane >> 3);
            int Ccol = (lane & 7) * 8;
            bf16x8 v = *(const bf16x8*)(ep + R * 104 + Ccol);
            *(bf16x8*)(Cw + (size_t)R * NB + Ccol) = v;
        }
        // cols 64..95: 4 insts, 16 rows x 4 lanes x 16B
#pragma unroll
        for (int p = 0; p < 4; ++p) {
            int R = p * 16 + (lane >> 2);
            int Ccol = 64 + (lane & 3) * 8;
            bf16x8 v = *(const bf16x8*)(ep + R * 104 + Ccol);
            *(bf16x8*)(Cw + (size_t)R * NB + Ccol) = v;
        }
        __syncthreads();
    }
}

// ---------------------------------------------------------------------------
// final: wave-per-token, 4 tokens/block, zero __syncthreads (unchanged).
// ---------------------------------------------------------------------------
__global__ __launch_bounds__(256) void final_kernel(const bf16* __restrict__ C,
                                                    const float* __restrict__ b1,
                                                    const float* __restrict__ b2,
                                                    const float* __restrict__ w2,
                                                    const float* __restrict__ cvec,
                                                    const float* __restrict__ merge_b,
                                                    const float* __restrict__ gamma,
                                                    const float* __restrict__ beta,
                                                    float* __restrict__ out) {
    const int wave = threadIdx.x >> 6, lane = threadIdx.x & 63;
    const int row = blockIdx.x * 4 + wave;
    const int t = row & (TT - 1);
    const bf16* Crow = C + (size_t)row * CN;

    const int h0 = lane * 8;
    bf16x8 u8 = *(const bf16x8*)(Crow + h0);
    float4 b1a = *(const float4*)(b1 + h0), b1b = *(const float4*)(b1 + h0 + 4);
    float4 w2a = *(const float4*)(w2 + h0), w2b = *(const float4*)(w2 + h0 + 4);
    float u[8] = {(float)u8[0] + b1a.x, (float)u8[1] + b1a.y,
                  (float)u8[2] + b1a.z, (float)u8[3] + b1a.w,
                  (float)u8[4] + b1b.x, (float)u8[5] + b1b.y,
                  (float)u8[6] + b1b.z, (float)u8[7] + b1b.w};
    const float w2v[8] = {w2a.x, w2a.y, w2a.z, w2a.w, w2b.x, w2b.y, w2b.z, w2b.w};

    float partial[4];
#pragma unroll
    for (int w = 0; w < 4; ++w) {
        float p = 0.f;
        if (t >= w + 1) {
            bf16x8 v8 = *(const bf16x8*)(C + (size_t)(row - w - 1) * CN + 512 + h0);
#pragma unroll
            for (int k = 0; k < 8; ++k) {
                float z = u[k] + (float)v8[k];
                p += (z / (1.f + __expf(-z))) * w2v[k];
            }
        } else {
#pragma unroll
            for (int k = 0; k < 8; ++k) {
                float z = u[k];
                p += (z / (1.f + __expf(-z))) * w2v[k];
            }
        }
        partial[w] = p;
    }
#pragma unroll
    for (int w = 0; w < 4; ++w)
#pragma unroll
        for (int off = 1; off < 64; off <<= 1)
            partial[w] += __shfl_xor(partial[w], off, 64);

    const float bias2 = b2[0];
    float taus[4];
#pragma unroll
    for (int w = 0; w < 4; ++w)
        taus[w] = 1.f / (1.f + __expf(-(partial[w] + bias2)));
    const float tsum = taus[0] + taus[1] + taus[2] + taus[3];

    const int d0 = lane * 16;
    bf16x8 y1a = *(const bf16x8*)(Crow + 2048 + d0);
    bf16x8 y1b = *(const bf16x8*)(Crow + 2048 + d0 + 8);
    float v[16];
#pragma unroll
    for (int k = 0; k < 8; ++k) { v[k] = (float)y1a[k]; v[8 + k] = (float)y1b[k]; }
#pragma unroll
    for (int q = 0; q < 4; ++q) {
        float4 cv = *(const float4*)(cvec + d0 + q * 4);
        float4 mb = *(const float4*)(merge_b + d0 + q * 4);
        v[q*4+0] += tsum * cv.x + mb.x; v[q*4+1] += tsum * cv.y + mb.y;
        v[q*4+2] += tsum * cv.z + mb.z; v[q*4+3] += tsum * cv.w + mb.w;
    }
#pragma unroll
    for (int w = 0; w < 4; ++w) {
        if (t >= w + 1) {
            const bf16* Pn = C + (size_t)(row - w - 1) * CN + 1024 + d0;
            bf16x8 pa = *(const bf16x8*)Pn;
            bf16x8 pb = *(const bf16x8*)(Pn + 8);
#pragma unroll
            for (int k = 0; k < 8; ++k) {
                v[k] += taus[w] * (float)pa[k];
                v[8 + k] += taus[w] * (float)pb[k];
            }
        }
    }

    float s = 0.f, ss = 0.f;
#pragma unroll
    for (int k = 0; k < 16; ++k) { s += v[k]; ss += v[k] * v[k]; }
#pragma unroll
    for (int off = 1; off < 64; off <<= 1) {
        s  += __shfl_xor(s, off, 64);
        ss += __shfl_xor(ss, off, 64);
    }
    const float mu = s * (1.f / TD);
    const float var = ss * (1.f / TD) - mu * mu;
    const float r = rsqrtf(var + EPS);

#pragma unroll
    for (int q = 0; q < 4; ++q) {
        float4 g  = *(const float4*)(gamma + d0 + q * 4);
        float4 bt = *(const float4*)(beta + d0 + q * 4);
        float4 o;
        o.x = (v[q*4+0] - mu) * r * g.x + bt.x;
        o.y = (v[q*4+1] - mu) * r * g.y + bt.y;
        o.z = (v[q*4+2] - mu) * r * g.z + bt.z;
        o.w = (v[q*4+3] - mu) * r * g.w + bt.w;
        *(float4*)(out + (size_t)row * TD + d0 + q * 4) = o;
    }
}

// ---------------------------------------------------------------------------
extern "C" void kernel_launch(void* const* d_in, const int* in_sizes, int n_in,
                              void* d_out, int out_size, void* d_ws, size_t ws_size,
                              hipStream_t stream) {
    const float* x       = (const float*)d_in[0];
    const float* w1      = (const float*)d_in[1];
    const float* b1      = (const float*)d_in[2];
    const float* w2      = (const float*)d_in[3];
    const float* b2      = (const float*)d_in[4];
    const float* wv_w    = (const float*)d_in[5];
    const float* wv_b    = (const float*)d_in[6];
    const float* merge_w = (const float*)d_in[7];
    const float* merge_b = (const float*)d_in[8];
    const float* gamma   = (const float*)d_in[9];
    const float* beta    = (const float*)d_in[10];
    float* out = (float*)d_out;

    char* ws = (char*)d_ws;
    bf16*  Xbf   = (bf16*)ws;  ws += (size_t)TM * 1024 * 2;    // [8192][1024]
    bf16*  BigBT = (bf16*)ws;  ws += (size_t)CN * 1024 * 2;    // [3072 n][1024 k]
    bf16*  Amb   = (bf16*)ws;  ws += (size_t)1024 * 1024 * 2;  // merge_bot^T [j][e]
    bf16*  WvBf  = (bf16*)ws;  ws += (size_t)1024 * 1024 * 2;  // wv_w bf16
    float* cvecP = (float*)ws; ws += (size_t)4 * 1024 * 4;     // partials
    float* cvec  = (float*)ws; ws += (size_t)1024 * 4;         // wv_b @ merge_bot
    bf16*  Cbuf  = (bf16*)ws;                                  // [8192][3072]

    // 1. marshal everything (one launch)
    prep_kernel<<<12304, 256, 0, stream>>>(x, w1, wv_w, wv_b, merge_w,
                                           Xbf, BigBT, Amb, WvBf, cvecP);

    // 2. W' GEMM (full-GPU 64x64 tiles) + cvec reduction
    wprime_kernel<<<257, 256, 0, stream>>>(Amb, WvBf, BigBT + (size_t)1024 * 1024,
                                           cvecP, cvec);

    // 3. big GEMM: Cbuf = Xbf @ BigBT^T   (M=8192, N=3072, K=1024)
    //    256x192 tiles, 4 waves of 128x96, 512 blocks = 2 exact passes
    gemm_big<<<512, 256, 0, stream>>>(Xbf, BigBT, Cbuf);

    // 4. fused tau + combine + LayerNorm (wave-per-token, no barriers)
    final_kernel<<<TM / 4, 256, 0, stream>>>(Cbuf, b1, b2, w2, cvec, merge_b,
                                             gamma, beta, out);
}

// Round 5
// 198.819 us; speedup vs baseline: 1.0523x; 1.0207x over previous
//
#include <hip/hip_runtime.h>
#include <hip/hip_bf16.h>

// Problem constants (B=2, T=4096, D=1024, H=512)
#define TT 4096
#define TD 1024
#define TM 8192            // B*T tokens
#define CN 3072            // big-GEMM N: [U 512 | Vn 512 | P 1024 | Y1 1024]
#define EPS 1e-5f

typedef __bf16 bf16;
typedef __bf16 bf16x4 __attribute__((ext_vector_type(4)));
typedef __bf16 bf16x8 __attribute__((ext_vector_type(8)));
typedef float  f32x4  __attribute__((ext_vector_type(4)));

#define GLOBAL_AS __attribute__((address_space(1)))
#define LDS_AS    __attribute__((address_space(3)))

// ---------------------------------------------------------------------------
// prep: one launch does all input marshalling (unchanged).
// ---------------------------------------------------------------------------
__global__ __launch_bounds__(256) void prep_kernel(const float* __restrict__ x,
                                                   const float* __restrict__ w1,
                                                   const float* __restrict__ wv_w,
                                                   const float* __restrict__ wv_b,
                                                   const float* __restrict__ merge_w,
                                                   bf16* __restrict__ Xbf,
                                                   bf16* __restrict__ BigBT,
                                                   bf16* __restrict__ Amb,
                                                   bf16* __restrict__ WvBf,
                                                   float* __restrict__ cvecP) {
    __shared__ float tile[32][33];
    int b = blockIdx.x;
    const int tid = threadIdx.x;

    if (b < 16) {  // cvec partials: jb = b&3 (256 j's), ec = b>>2 (256 e's)
        const int j = (b & 3) * 256 + tid;
        const int e0 = (b >> 2) * 256;
        const float* col = merge_w + (size_t)(1024 + e0) * 1024 + j;
        float acc = 0.f;
#pragma unroll 32
        for (int e = 0; e < 256; ++e) acc += wv_b[e0 + e] * col[(size_t)e * 1024];
        cvecP[(b >> 2) * 1024 + j] = acc;
        return;
    }
    b -= 16;
    if (b < 8192) {  // cast x
        int i = b * 256 + tid;
        float4 v = ((const float4*)x)[i];
        bf16x4 o; o[0] = (bf16)v.x; o[1] = (bf16)v.y; o[2] = (bf16)v.z; o[3] = (bf16)v.w;
        *(bf16x4*)(Xbf + (size_t)i * 4) = o;
        return;
    }
    b -= 8192;

    const float* src; bf16* dst; int srcN, tilesX, dstOff;
    if (b < 512)       {            src = w1;                        srcN = 512;  tilesX = 16; dst = BigBT; dstOff = 0;    }
    else if (b < 1024) { b -= 512;  src = w1 + (size_t)1024 * 512;   srcN = 512;  tilesX = 16; dst = BigBT; dstOff = 512;  }
    else if (b < 2048) { b -= 1024; src = merge_w;                   srcN = 1024; tilesX = 32; dst = BigBT; dstOff = 2048; }
    else if (b < 3072) { b -= 2048; src = merge_w + (size_t)1024 * 1024; srcN = 1024; tilesX = 32; dst = Amb; dstOff = 0; }
    else {  // cast wv_w
        b -= 3072;
        int i = b * 256 + tid;
        float4 v = ((const float4*)wv_w)[i];
        bf16x4 o; o[0] = (bf16)v.x; o[1] = (bf16)v.y; o[2] = (bf16)v.z; o[3] = (bf16)v.w;
        *(bf16x4*)(WvBf + (size_t)i * 4) = o;
        return;
    }
    int n0 = (b % tilesX) * 32, k0 = (b / tilesX) * 32;
    int tx = tid & 31, ty = tid >> 5;
#pragma unroll
    for (int r = 0; r < 32; r += 8)
        tile[ty + r][tx] = src[(size_t)(k0 + ty + r) * srcN + n0 + tx];
    __syncthreads();
#pragma unroll
    for (int r = 0; r < 32; r += 8)
        dst[(size_t)(dstOff + n0 + ty + r) * 1024 + k0 + tx] = (bf16)tile[tx][ty + r];
}

// ---------------------------------------------------------------------------
// wprime: W' GEMM on 64x64 tiles (grid 257) + cvec reduction (unchanged)
// ---------------------------------------------------------------------------
__global__ __launch_bounds__(256) void wprime_kernel(const bf16* __restrict__ Amb,
                                                     const bf16* __restrict__ WvBf,
                                                     bf16* __restrict__ Wout,
                                                     const float* __restrict__ cvecP,
                                                     float* __restrict__ cvec) {
    int b = blockIdx.x;
    if (b == 256) {
        int j = threadIdx.x * 4;
        float4 s0 = *(const float4*)(cvecP + j);
        float4 s1 = *(const float4*)(cvecP + 1024 + j);
        float4 s2 = *(const float4*)(cvecP + 2048 + j);
        float4 s3 = *(const float4*)(cvecP + 3072 + j);
        float4 o = {s0.x + s1.x + s2.x + s3.x, s0.y + s1.y + s2.y + s3.y,
                    s0.z + s1.z + s2.z + s3.z, s0.w + s1.w + s2.w + s3.w};
        *(float4*)(cvec + j) = o;
        return;
    }
    __shared__ bf16 As[64 * 64];
    __shared__ bf16 Bs[64 * 64];
    const int m0 = (b >> 4) * 64;
    const int n0 = (b & 15) * 64;
    const int tid = threadIdx.x;
    const int wave = tid >> 6, lane = tid & 63;
    const int wr = (wave >> 1) * 32, wc = (wave & 1) * 32;
    const int lrow = lane & 15, cbase = lane >> 4;
    const int sw = lrow & 7;

    f32x4 acc[2][2] = {};

    for (int k0 = 0; k0 < 1024; k0 += 64) {
        __syncthreads();
#pragma unroll
        for (int c = 0; c < 2; ++c) {
            int e = (c * 256 + tid) * 8;
            int row = e >> 6;
            int q = (e >> 3) & 7;
            int gcol = ((q ^ (row & 7)) << 3);
            const bf16* ga = Amb  + (size_t)(m0 + row) * 1024 + k0 + gcol;
            const bf16* gb = WvBf + (size_t)(n0 + row) * 1024 + k0 + gcol;
            __builtin_amdgcn_global_load_lds((const GLOBAL_AS void*)ga,
                                             (LDS_AS void*)(As + e), 16, 0, 0);
            __builtin_amdgcn_global_load_lds((const GLOBAL_AS void*)gb,
                                             (LDS_AS void*)(Bs + e), 16, 0, 0);
        }
        __syncthreads();

#pragma unroll
        for (int kk = 0; kk < 2; ++kk) {
            const int qo = ((cbase + kk * 4) ^ sw) << 3;
            bf16x8 af[2], bfr[2];
#pragma unroll
            for (int i = 0; i < 2; ++i) {
                af[i]  = *(const bf16x8*)(As + (wr + i * 16 + lrow) * 64 + qo);
                bfr[i] = *(const bf16x8*)(Bs + (wc + i * 16 + lrow) * 64 + qo);
            }
#pragma unroll
            for (int i = 0; i < 2; ++i)
#pragma unroll
                for (int j = 0; j < 2; ++j)
                    acc[i][j] = __builtin_amdgcn_mfma_f32_16x16x32_bf16(af[i], bfr[j], acc[i][j], 0, 0, 0);
        }
    }

    const int lr = (lane >> 4) * 4, lc = lane & 15;
#pragma unroll
    for (int i = 0; i < 2; ++i)
#pragma unroll
        for (int j = 0; j < 2; ++j)
#pragma unroll
            for (int r = 0; r < 4; ++r)
                Wout[(size_t)(m0 + wr + i * 16 + lr + r) * 1024 + (n0 + wc + j * 16 + lc)]
                    = (bf16)acc[i][j][r];
}

// ---------------------------------------------------------------------------
// Big GEMM v5 = r1 geometry + v4's conflict-free LDS layout.
//
// Resource model (the r3/r4 lesson, restated correctly):
//  - LDS is ONE shared pipe per CU (~85-100 B/cyc); MFMA is 4 parallel
//    pipes (one per SIMD). Compare LDS-cycles vs per-SIMD MFMA-cycles.
//  - 8 waves of 64x96 (2 waves/SIMD): frag 160KB + stage 57KB ~= 2500
//    LDS-cyc/K-tile vs 1546 MFMA-cyc/SIMD -> ceiling ~62% MfmaUtil ~33us.
//  - v4's 4 waves (1/SIMD) has the same ceiling but NO TLP: every ds_read
//    latency + gate stall is exposed (measured 4800 cyc/K-tile, Occ 9.7%).
//  - r1 WAS this structure and ran 59us, but carried a 2.49M-cycle bank
//    conflict from K-halved 32-col A slots (bad XOR: only 2 chunk positions
//    per even/odd row set). Fix: full-K 64-col slots with the 8-chunk XOR
//    verified conflict-free in r0/r4 (393K).
//
// Geometry: BM=256 x BN=192, BK=64, 512 thr / 8 waves (4M x 2N), wave 64x96
// (acc[4][6]=96 regs -> no spill at (512,2), proven by r1's VGPR=96).
// LDS 112 KiB: 2 buf x (A 256x64 + B 192x64). Grid 512 = 2 exact passes.
// Staging: A(t+1) at p0 (4 loads), B(t+1) at p1 (3 loads), GATE0 at p3
// (~2.5 phases between issue and drain). XCD: stripes {2x,2x+1} per XCD.
// ---------------------------------------------------------------------------
#define MFMA16(a, b, c) __builtin_amdgcn_mfma_f32_16x16x32_bf16((a), (b), (c), 0, 0, 0)

// LDS (bf16 el): buf = BUF*28672.  A at +0 (256x64=16384), B at +16384 (192x64=12288)
#define STAGE_A(BUF, T) do {                                                      \
    _Pragma("unroll")                                                             \
    for (int ld_ = 0; ld_ < 4; ++ld_) {                                           \
        const bf16* ga_ = aBase + (size_t)(ld_ * 64) * 1024 + (T) * 64;           \
        __builtin_amdgcn_global_load_lds((const GLOBAL_AS void*)ga_,              \
            (LDS_AS void*)(SMEM + (BUF) * 28672 + ld_ * 4096 + tid * 8), 16, 0, 0); \
    } } while (0)

#define STAGE_B(BUF, T) do {                                                      \
    _Pragma("unroll")                                                             \
    for (int ld_ = 0; ld_ < 3; ++ld_) {                                           \
        const bf16* gb_ = bBase + (size_t)(ld_ * 64) * 1024 + (T) * 64;           \
        __builtin_amdgcn_global_load_lds((const GLOBAL_AS void*)gb_,              \
            (LDS_AS void*)(SMEM + (BUF) * 28672 + 16384 + ld_ * 4096 + tid * 8), 16, 0, 0); \
    } } while (0)

#define AF(BUF, I, KK) (*(const bf16x8*)(SMEM + (BUF) * 28672 +                   \
    (wm * 64 + (I) * 16 + lrow) * 64 + (((cbase + (KK) * 4) ^ sw) << 3)))
#define BF(BUF, J, KK) (*(const bf16x8*)(SMEM + (BUF) * 28672 + 16384 +           \
    (wn * 96 + (J) * 16 + lrow) * 64 + (((cbase + (KK) * 4) ^ sw) << 3)))

#define NOSTAGE do {} while (0)
#define NOGATE  do {} while (0)
#define GATE0 do { asm volatile("s_waitcnt vmcnt(0)" ::: "memory");               \
                   __builtin_amdgcn_sched_barrier(0); } while (0)

// Phase: (KK, H): A-frags i = H*2, H*2+1; 12 MFMA. RDB: refresh bfr[] for KK.
#define PH(BUF, KK, H, RDB, STAGE, GATE) do {                                     \
    if (RDB) {                                                                    \
        _Pragma("unroll")                                                         \
        for (int j = 0; j < 6; ++j) bfr[j] = BF(BUF, j, KK);                      \
    }                                                                             \
    bf16x8 a0_ = AF(BUF, (H) * 2 + 0, KK);                                        \
    bf16x8 a1_ = AF(BUF, (H) * 2 + 1, KK);                                        \
    STAGE;                                                                        \
    __builtin_amdgcn_s_barrier();                                                 \
    __builtin_amdgcn_sched_barrier(0);                                            \
    __builtin_amdgcn_s_setprio(1);                                                \
    _Pragma("unroll")                                                             \
    for (int j = 0; j < 6; ++j) {                                                 \
        acc[(H) * 2 + 0][j] = MFMA16(a0_, bfr[j], acc[(H) * 2 + 0][j]);           \
        acc[(H) * 2 + 1][j] = MFMA16(a1_, bfr[j], acc[(H) * 2 + 1][j]);           \
    }                                                                             \
    __builtin_amdgcn_s_setprio(0);                                                \
    GATE;                                                                         \
    __builtin_amdgcn_s_barrier();                                                 \
    __builtin_amdgcn_sched_barrier(0);                                            \
} while (0)

// One K-tile (4 phases). SA/SB stage tile t+1; gate at p3.
#define TILE(BUF, SA, SB, G3)                                                     \
    PH(BUF, 0, 0, 1, SA, NOGATE);                                                 \
    PH(BUF, 0, 1, 0, SB, NOGATE);                                                 \
    PH(BUF, 1, 0, 1, NOSTAGE, NOGATE);                                            \
    PH(BUF, 1, 1, 0, NOSTAGE, G3);

__global__ __launch_bounds__(512, 2) void gemm_big(const bf16* __restrict__ A,
                                                   const bf16* __restrict__ BT,
                                                   bf16* __restrict__ C) {
    __shared__ __align__(16) bf16 SMEM[57344];   // 114688 B = 112 KiB
    const int NB = 3072, K = 1024;

    const int L = blockIdx.x;            // 0..511
    const int m0 = (L >> 4) * 256;       // 32 M-tiles
    const int n0 = ((L & 7) * 2 + ((L >> 3) & 1)) * 192;  // XCD x -> stripes {2x,2x+1}
    const int tid = threadIdx.x;
    const int wave = tid >> 6, lane = tid & 63;
    const int wm = wave >> 1;            // 0..3 -> M offset wm*64
    const int wn = wave & 1;             // 0..1 -> N offset wn*96
    const int lrow = lane & 15, cbase = lane >> 4;
    const int sw = lrow & 7;

    // staging source bases (pre-swizzled; ld/t offsets added in macros)
    const int r0 = tid >> 3;                               // 0..63
    const int c0 = ((tid & 7) ^ ((tid >> 3) & 7)) << 3;    // 8-chunk XOR col
    const bf16* aBase = A  + (size_t)(m0 + r0) * K + c0;
    const bf16* bBase = BT + (size_t)(n0 + r0) * K + c0;

    f32x4 acc[4][6] = {};
    bf16x8 bfr[6];

    // ---- prologue: stage tile 0 fully, drain, barrier ----
    STAGE_A(0, 0);
    STAGE_B(0, 0);
    asm volatile("s_waitcnt vmcnt(0)" ::: "memory");
    __builtin_amdgcn_sched_barrier(0);
    __builtin_amdgcn_s_barrier();
    __builtin_amdgcn_sched_barrier(0);

    // ---- main loop: tiles 0..13 (7 iters x 2 tiles), staging 1 tile ahead
    for (int i = 0; i < 7; ++i) {
        const int t1 = 2 * i + 1, t2 = 2 * i + 2;
        TILE(0, STAGE_A(1, t1), STAGE_B(1, t1), GATE0);
        TILE(1, STAGE_A(0, t2), STAGE_B(0, t2), GATE0);
    }
    // tile 14 (stage 15), tile 15 (no stage)
    TILE(0, STAGE_A(1, 15), STAGE_B(1, 15), GATE0);
    TILE(1, NOSTAGE, NOSTAGE, NOGATE);

    // ---- Epilogue: repack via LDS (wave-local region, stride 104 bf16) ----
    __syncthreads();                       // all waves done with staging LDS
    bf16* ep = SMEM + wave * 6656;         // 64 rows x 104 stride (53248 el total)
    const int lr = (lane >> 4) * 4, lc = lane & 15;
#pragma unroll
    for (int i = 0; i < 4; ++i)
#pragma unroll
        for (int j = 0; j < 6; ++j)
#pragma unroll
            for (int r = 0; r < 4; ++r)
                ep[(i * 16 + lr + r) * 104 + (j * 16 + lc)] = (bf16)acc[i][j][r];
    __syncthreads();

    bf16* Cw = C + (size_t)(m0 + wm * 64) * NB + n0 + wn * 96;
    // cols 0..63: 8 insts, 8 rows x 8 lanes x 16B
#pragma unroll
    for (int p = 0; p < 8; ++p) {
        int R = p * 8 + (lane >> 3);
        int Ccol = (lane & 7) * 8;
        bf16x8 v = *(const bf16x8*)(ep + R * 104 + Ccol);
        *(bf16x8*)(Cw + (size_t)R * NB + Ccol) = v;
    }
    // cols 64..95: 4 insts, 16 rows x 4 lanes x 16B
#pragma unroll
    for (int p = 0; p < 4; ++p) {
        int R = p * 16 + (lane >> 2);
        int Ccol = 64 + (lane & 3) * 8;
        bf16x8 v = *(const bf16x8*)(ep + R * 104 + Ccol);
        *(bf16x8*)(Cw + (size_t)R * NB + Ccol) = v;
    }
}

// ---------------------------------------------------------------------------
// final: wave-per-token, 4 tokens/block, zero __syncthreads (unchanged).
// ---------------------------------------------------------------------------
__global__ __launch_bounds__(256) void final_kernel(const bf16* __restrict__ C,
                                                    const float* __restrict__ b1,
                                                    const float* __restrict__ b2,
                                                    const float* __restrict__ w2,
                                                    const float* __restrict__ cvec,
                                                    const float* __restrict__ merge_b,
                                                    const float* __restrict__ gamma,
                                                    const float* __restrict__ beta,
                                                    float* __restrict__ out) {
    const int wave = threadIdx.x >> 6, lane = threadIdx.x & 63;
    const int row = blockIdx.x * 4 + wave;
    const int t = row & (TT - 1);
    const bf16* Crow = C + (size_t)row * CN;

    const int h0 = lane * 8;
    bf16x8 u8 = *(const bf16x8*)(Crow + h0);
    float4 b1a = *(const float4*)(b1 + h0), b1b = *(const float4*)(b1 + h0 + 4);
    float4 w2a = *(const float4*)(w2 + h0), w2b = *(const float4*)(w2 + h0 + 4);
    float u[8] = {(float)u8[0] + b1a.x, (float)u8[1] + b1a.y,
                  (float)u8[2] + b1a.z, (float)u8[3] + b1a.w,
                  (float)u8[4] + b1b.x, (float)u8[5] + b1b.y,
                  (float)u8[6] + b1b.z, (float)u8[7] + b1b.w};
    const float w2v[8] = {w2a.x, w2a.y, w2a.z, w2a.w, w2b.x, w2b.y, w2b.z, w2b.w};

    float partial[4];
#pragma unroll
    for (int w = 0; w < 4; ++w) {
        float p = 0.f;
        if (t >= w + 1) {
            bf16x8 v8 = *(const bf16x8*)(C + (size_t)(row - w - 1) * CN + 512 + h0);
#pragma unroll
            for (int k = 0; k < 8; ++k) {
                float z = u[k] + (float)v8[k];
                p += (z / (1.f + __expf(-z))) * w2v[k];
            }
        } else {
#pragma unroll
            for (int k = 0; k < 8; ++k) {
                float z = u[k];
                p += (z / (1.f + __expf(-z))) * w2v[k];
            }
        }
        partial[w] = p;
    }
#pragma unroll
    for (int w = 0; w < 4; ++w)
#pragma unroll
        for (int off = 1; off < 64; off <<= 1)
            partial[w] += __shfl_xor(partial[w], off, 64);

    const float bias2 = b2[0];
    float taus[4];
#pragma unroll
    for (int w = 0; w < 4; ++w)
        taus[w] = 1.f / (1.f + __expf(-(partial[w] + bias2)));
    const float tsum = taus[0] + taus[1] + taus[2] + taus[3];

    const int d0 = lane * 16;
    bf16x8 y1a = *(const bf16x8*)(Crow + 2048 + d0);
    bf16x8 y1b = *(const bf16x8*)(Crow + 2048 + d0 + 8);
    float v[16];
#pragma unroll
    for (int k = 0; k < 8; ++k) { v[k] = (float)y1a[k]; v[8 + k] = (float)y1b[k]; }
#pragma unroll
    for (int q = 0; q < 4; ++q) {
        float4 cv = *(const float4*)(cvec + d0 + q * 4);
        float4 mb = *(const float4*)(merge_b + d0 + q * 4);
        v[q*4+0] += tsum * cv.x + mb.x; v[q*4+1] += tsum * cv.y + mb.y;
        v[q*4+2] += tsum * cv.z + mb.z; v[q*4+3] += tsum * cv.w + mb.w;
    }
#pragma unroll
    for (int w = 0; w < 4; ++w) {
        if (t >= w + 1) {
            const bf16* Pn = C + (size_t)(row - w - 1) * CN + 1024 + d0;
            bf16x8 pa = *(const bf16x8*)Pn;
            bf16x8 pb = *(const bf16x8*)(Pn + 8);
#pragma unroll
            for (int k = 0; k < 8; ++k) {
                v[k] += taus[w] * (float)pa[k];
                v[8 + k] += taus[w] * (float)pb[k];
            }
        }
    }

    float s = 0.f, ss = 0.f;
#pragma unroll
    for (int k = 0; k < 16; ++k) { s += v[k]; ss += v[k] * v[k]; }
#pragma unroll
    for (int off = 1; off < 64; off <<= 1) {
        s  += __shfl_xor(s, off, 64);
        ss += __shfl_xor(ss, off, 64);
    }
    const float mu = s * (1.f / TD);
    const float var = ss * (1.f / TD) - mu * mu;
    const float r = rsqrtf(var + EPS);

#pragma unroll
    for (int q = 0; q < 4; ++q) {
        float4 g  = *(const float4*)(gamma + d0 + q * 4);
        float4 bt = *(const float4*)(beta + d0 + q * 4);
        float4 o;
        o.x = (v[q*4+0] - mu) * r * g.x + bt.x;
        o.y = (v[q*4+1] - mu) * r * g.y + bt.y;
        o.z = (v[q*4+2] - mu) * r * g.z + bt.z;
        o.w = (v[q*4+3] - mu) * r * g.w + bt.w;
        *(float4*)(out + (size_t)row * TD + d0 + q * 4) = o;
    }
}

// ---------------------------------------------------------------------------
extern "C" void kernel_launch(void* const* d_in, const int* in_sizes, int n_in,
                              void* d_out, int out_size, void* d_ws, size_t ws_size,
                              hipStream_t stream) {
    const float* x       = (const float*)d_in[0];
    const float* w1      = (const float*)d_in[1];
    const float* b1      = (const float*)d_in[2];
    const float* w2      = (const float*)d_in[3];
    const float* b2      = (const float*)d_in[4];
    const float* wv_w    = (const float*)d_in[5];
    const float* wv_b    = (const float*)d_in[6];
    const float* merge_w = (const float*)d_in[7];
    const float* merge_b = (const float*)d_in[8];
    const float* gamma   = (const float*)d_in[9];
    const float* beta    = (const float*)d_in[10];
    float* out = (float*)d_out;

    char* ws = (char*)d_ws;
    bf16*  Xbf   = (bf16*)ws;  ws += (size_t)TM * 1024 * 2;    // [8192][1024]
    bf16*  BigBT = (bf16*)ws;  ws += (size_t)CN * 1024 * 2;    // [3072 n][1024 k]
    bf16*  Amb   = (bf16*)ws;  ws += (size_t)1024 * 1024 * 2;  // merge_bot^T [j][e]
    bf16*  WvBf  = (bf16*)ws;  ws += (size_t)1024 * 1024 * 2;  // wv_w bf16
    float* cvecP = (float*)ws; ws += (size_t)4 * 1024 * 4;     // partials
    float* cvec  = (float*)ws; ws += (size_t)1024 * 4;         // wv_b @ merge_bot
    bf16*  Cbuf  = (bf16*)ws;                                  // [8192][3072]

    // 1. marshal everything (one launch)
    prep_kernel<<<12304, 256, 0, stream>>>(x, w1, wv_w, wv_b, merge_w,
                                           Xbf, BigBT, Amb, WvBf, cvecP);

    // 2. W' GEMM (full-GPU 64x64 tiles) + cvec reduction
    wprime_kernel<<<257, 256, 0, stream>>>(Amb, WvBf, BigBT + (size_t)1024 * 1024,
                                           cvecP, cvec);

    // 3. big GEMM: Cbuf = Xbf @ BigBT^T   (M=8192, N=3072, K=1024)
    //    256x192 tiles, 8 waves of 64x96, 512 blocks = 2 exact passes
    gemm_big<<<512, 512, 0, stream>>>(Xbf, BigBT, Cbuf);

    // 4. fused tau + combine + LayerNorm (wave-per-token, no barriers)
    final_kernel<<<TM / 4, 256, 0, stream>>>(Cbuf, b1, b2, w2, cvec, merge_b,
                                             gamma, beta, out);
}